// Round 2
// baseline (274.874 us; speedup 1.0000x reference)
//
#include <hip/hip_runtime.h>

#define N 8192
#define D 128

using short8  = __attribute__((ext_vector_type(8))) short;
using float4v = __attribute__((ext_vector_type(4))) float;

// float -> bf16 (RNE) as raw ushort
static __device__ inline unsigned int f2bf(float f) {
    union { float f; unsigned int u; } x;
    x.f = f;
    unsigned int u = x.u;
    return (u + 0x7FFFu + ((u >> 16) & 1u)) >> 16;
}

// Each block: 128 rows x 512 cols of the 8192^2 similarity matrix.
// Grid = (64 row-blocks, 16 column-splits) = 1024 blocks, 4 blocks/CU.
// Last block (ticket) computes the final mean loss (validity == pos>0,
// since pos[i] is a sum of strictly positive exp terms).
__global__ __launch_bounds__(256, 4) void cl_main(
    const float* __restrict__ emb, const int* __restrict__ labels,
    float* __restrict__ tot, float* __restrict__ pos,
    int* __restrict__ ticket, float* __restrict__ out)
{
    __shared__ uint4 ldsB[128 * 16];  // 128x128 bf16 tile, 16B chunks, XOR-swizzled (32 KB)
    __shared__ float sred[2][4];
    __shared__ int s_ticket;

    const int tid  = threadIdx.x;
    const int lane = tid & 63;
    const int wave = tid >> 6;
    const int q    = lane >> 4;   // quad id 0..3
    const int c    = lane & 15;   // low-4 lane id
    const int rw   = blockIdx.x * 128 + wave * 32;   // this wave's 32-row base

    // ---- A fragments: this wave's 32 rows, fp32->bf16 in regs, loaded once ----
    // A-operand layout (16x16x32): m = lane&15, k = q*8 + j
    short8 afrag[2][4];
    int rowlab[2][4];
    #pragma unroll
    for (int tr = 0; tr < 2; ++tr) {
        const int arow = rw + tr * 16 + c;
        #pragma unroll
        for (int ks = 0; ks < 4; ++ks) {
            const float* p = emb + arow * D + ks * 32 + q * 8;
            float4v f0 = *(const float4v*)p;
            float4v f1 = *(const float4v*)(p + 4);
            short8 a;
            a[0] = (short)f2bf(f0[0]); a[1] = (short)f2bf(f0[1]);
            a[2] = (short)f2bf(f0[2]); a[3] = (short)f2bf(f0[3]);
            a[4] = (short)f2bf(f1[0]); a[5] = (short)f2bf(f1[1]);
            a[6] = (short)f2bf(f1[2]); a[7] = (short)f2bf(f1[3]);
            afrag[tr][ks] = a;
        }
        // C/D layout rows this lane owns: rw + tr*16 + q*4 + reg
        #pragma unroll
        for (int reg = 0; reg < 4; ++reg)
            rowlab[tr][reg] = labels[rw + tr * 16 + q * 4 + reg];
    }

    float tot_a[2][4] = {{0.f,0.f,0.f,0.f},{0.f,0.f,0.f,0.f}};
    float pos_a[2][4] = {{0.f,0.f,0.f,0.f},{0.f,0.f,0.f,0.f}};
    const float invT = 1.0f / 0.07f;

    for (int it = 0; it < 4; ++it) {
        const int cbase = blockIdx.y * 512 + it * 128;

        // ---- stage 128x128 col tile: global fp32 -> bf16 LDS (swizzled) ----
        #pragma unroll
        for (int i = 0; i < 8; ++i) {
            const int g     = tid + i * 256;
            const int brow  = g >> 4;
            const int chunk = g & 15;
            const float* p = emb + (cbase + brow) * D + chunk * 8;
            float4v f0 = *(const float4v*)p;
            float4v f1 = *(const float4v*)(p + 4);
            uint4 u;
            u.x = f2bf(f0[0]) | (f2bf(f0[1]) << 16);
            u.y = f2bf(f0[2]) | (f2bf(f0[3]) << 16);
            u.z = f2bf(f1[0]) | (f2bf(f1[1]) << 16);
            u.w = f2bf(f1[2]) | (f2bf(f1[3]) << 16);
            ldsB[brow * 16 + (chunk ^ (brow & 15))] = u;
        }
        int collab[8];
        #pragma unroll
        for (int tc = 0; tc < 8; ++tc) collab[tc] = labels[cbase + tc * 16 + c];
        __syncthreads();

        // ---- MFMA: 2 tile-rows x 8 tile-cols, K=128 in 4 steps ----
        float4v acc[2][8];
        #pragma unroll
        for (int tr = 0; tr < 2; ++tr)
            #pragma unroll
            for (int tc = 0; tc < 8; ++tc) {
                float4v z = {0.f, 0.f, 0.f, 0.f};
                acc[tr][tc] = z;
            }

        const short8* ldsS = (const short8*)ldsB;
        #pragma unroll
        for (int ks = 0; ks < 4; ++ks) {
            #pragma unroll
            for (int tc = 0; tc < 8; ++tc) {
                const int brow  = tc * 16 + c;        // B-operand: n = lane&15
                const int chunk = ks * 4 + q;         // k-chunk index
                short8 b = ldsS[brow * 16 + (chunk ^ (brow & 15))];
                #pragma unroll
                for (int tr = 0; tr < 2; ++tr)
                    acc[tr][tc] = __builtin_amdgcn_mfma_f32_16x16x32_bf16(
                        afrag[tr][ks], b, acc[tr][tc], 0, 0, 0);
            }
        }

        // ---- epilogue: exp, diagonal/label masking, per-row accumulate ----
        #pragma unroll
        for (int tr = 0; tr < 2; ++tr) {
            const int rtile = rw + tr * 16;
            #pragma unroll
            for (int tc = 0; tc < 8; ++tc) {
                const bool diag_tile = (rtile == cbase + tc * 16);  // wave-uniform
                const int lc = collab[tc];
                #pragma unroll
                for (int reg = 0; reg < 4; ++reg) {
                    float v = __expf(acc[tr][tc][reg] * invT);
                    if (diag_tile && (q * 4 + reg) == c) v = 0.f;  // r == c
                    tot_a[tr][reg] += v;
                    if (rowlab[tr][reg] == lc) pos_a[tr][reg] += v;
                }
            }
        }
        __syncthreads();  // all LDS reads done before next staging
    }

    // ---- reduce over the 16 column-lanes, one atomic per row ----
    #pragma unroll
    for (int tr = 0; tr < 2; ++tr)
        #pragma unroll
        for (int reg = 0; reg < 4; ++reg) {
            float t = tot_a[tr][reg];
            float p = pos_a[tr][reg];
            #pragma unroll
            for (int m = 1; m < 16; m <<= 1) {
                t += __shfl_xor(t, m, 64);
                p += __shfl_xor(p, m, 64);
            }
            if (c == 0) {
                const int r = rw + tr * 16 + q * 4 + reg;
                atomicAdd(&tot[r], t);
                atomicAdd(&pos[r], p);
            }
        }

    // ---- last-block finalize (ticket pattern) ----
    __threadfence();                 // all threads: order our atomics
    __syncthreads();
    if (tid == 0)
        s_ticket = __hip_atomic_fetch_add(ticket, 1, __ATOMIC_ACQ_REL,
                                          __HIP_MEMORY_SCOPE_AGENT);
    __syncthreads();
    if (s_ticket != 64 * 16 - 1) return;   // not the last block

    __threadfence();
    float lsum = 0.f, lcnt = 0.f;
    for (int i = tid; i < N; i += 256) {
        const float t = __hip_atomic_load(&tot[i], __ATOMIC_RELAXED,
                                          __HIP_MEMORY_SCOPE_AGENT);
        const float p = __hip_atomic_load(&pos[i], __ATOMIC_RELAXED,
                                          __HIP_MEMORY_SCOPE_AGENT);
        const float loss = -__logf(p / (t + 1e-8f) + 1e-8f);
        if (p > 0.f) { lsum += loss; lcnt += 1.f; }
    }
    #pragma unroll
    for (int m = 1; m < 64; m <<= 1) {
        lsum += __shfl_xor(lsum, m, 64);
        lcnt += __shfl_xor(lcnt, m, 64);
    }
    if (lane == 0) { sred[0][wave] = lsum; sred[1][wave] = lcnt; }
    __syncthreads();
    if (tid == 0) {
        const float s = sred[0][0] + sred[0][1] + sred[0][2] + sred[0][3];
        const float n = sred[1][0] + sred[1][1] + sred[1][2] + sred[1][3];
        out[0] = (n > 0.f) ? s / fmaxf(n, 1.f) : 0.f;
    }
}

extern "C" void kernel_launch(void* const* d_in, const int* in_sizes, int n_in,
                              void* d_out, int out_size, void* d_ws, size_t ws_size,
                              hipStream_t stream) {
    const float* emb   = (const float*)d_in[0];
    const int* labels  = (const int*)d_in[1];
    float* tot    = (float*)d_ws;
    float* pos    = tot + N;
    int*   ticket = (int*)(pos + N);

    hipMemsetAsync(d_ws, 0, (2 * N + 1) * sizeof(float), stream);
    cl_main<<<dim3(64, 16), 256, 0, stream>>>(emb, labels, tot, pos, ticket,
                                              (float*)d_out);
}

// Round 3
// 196.521 us; speedup vs baseline: 1.3987x; 1.3987x over previous
//
#include <hip/hip_runtime.h>

#define N 8192
#define D 128
// (1/0.07) * log2(e): fold temperature AND base-2 conversion into A-side scale
#define SCALE_A 20.6098592f

using short8  = __attribute__((ext_vector_type(8))) short;
using float4v = __attribute__((ext_vector_type(4))) float;

#if __has_builtin(__builtin_amdgcn_exp2f)
#define EXP2(x) __builtin_amdgcn_exp2f(x)
#else
#define EXP2(x) __expf((x) * 0.69314718f)
#endif

// float -> bf16 (RNE) as raw ushort
static __device__ inline unsigned int f2bf(float f) {
    union { float f; unsigned int u; } x;
    x.f = f;
    unsigned int u = x.u;
    return (u + 0x7FFFu + ((u >> 16) & 1u)) >> 16;
}

// Pre-pass: emb fp32 -> bf16 (unscaled, B-side) and bf16*SCALE_A (A-side).
// Also zeroes tot/pos and the ticket. 65536 threads x 16 elements.
__global__ __launch_bounds__(256) void cl_prep(
    const float* __restrict__ emb, unsigned short* __restrict__ bfB,
    unsigned short* __restrict__ bfA, float* __restrict__ tot,
    int* __restrict__ ticket)
{
    const int t = blockIdx.x * 256 + threadIdx.x;
    const float* p = emb + (size_t)t * 16;
    uint4 ob[2], oa[2];
    #pragma unroll
    for (int h = 0; h < 2; ++h) {
        float4v f0 = *(const float4v*)(p + h * 8);
        float4v f1 = *(const float4v*)(p + h * 8 + 4);
        ob[h].x = f2bf(f0[0]) | (f2bf(f0[1]) << 16);
        ob[h].y = f2bf(f0[2]) | (f2bf(f0[3]) << 16);
        ob[h].z = f2bf(f1[0]) | (f2bf(f1[1]) << 16);
        ob[h].w = f2bf(f1[2]) | (f2bf(f1[3]) << 16);
        oa[h].x = f2bf(f0[0] * SCALE_A) | (f2bf(f0[1] * SCALE_A) << 16);
        oa[h].y = f2bf(f0[2] * SCALE_A) | (f2bf(f0[3] * SCALE_A) << 16);
        oa[h].z = f2bf(f1[0] * SCALE_A) | (f2bf(f1[1] * SCALE_A) << 16);
        oa[h].w = f2bf(f1[2] * SCALE_A) | (f2bf(f1[3] * SCALE_A) << 16);
    }
    ((uint4*)bfB)[t * 2]     = ob[0];
    ((uint4*)bfB)[t * 2 + 1] = ob[1];
    ((uint4*)bfA)[t * 2]     = oa[0];
    ((uint4*)bfA)[t * 2 + 1] = oa[1];
    if (t < 2 * N) tot[t] = 0.f;    // tot and pos are contiguous
    if (t == 0) *ticket = 0;
}

// Each block: 128 rows x 512 cols. Grid (64,16) = 1024 blocks.
// exp2(dot(A_scaled, B)) == exp(sim/T). Last block (ticket) finalizes.
__global__ __launch_bounds__(256, 3) void cl_main(
    const unsigned short* __restrict__ bfA, const unsigned short* __restrict__ bfB,
    const int* __restrict__ labels,
    float* __restrict__ tot, float* __restrict__ pos,
    int* __restrict__ ticket, float* __restrict__ out)
{
    __shared__ uint4 ldsB[128 * 16];  // 128x128 bf16 tile, 16B chunks, XOR-swizzled
    __shared__ float sred[2][4];
    __shared__ int s_ticket;

    const int tid  = threadIdx.x;
    const int lane = tid & 63;
    const int wave = tid >> 6;
    const int q    = lane >> 4;   // quad id 0..3
    const int c    = lane & 15;
    const int r4   = lane >> 4;   // staging row-within-group
    const int rw   = blockIdx.x * 128 + wave * 32;

    // ---- A fragments: 16B loads from prescaled bf16 array, once per block ----
    // A-operand layout (16x16x32): m = lane&15, k = q*8 + j
    short8 afrag[2][4];
    int rowlab[2][4];
    #pragma unroll
    for (int tr = 0; tr < 2; ++tr) {
        const int arow = rw + tr * 16 + c;
        #pragma unroll
        for (int ks = 0; ks < 4; ++ks)
            afrag[tr][ks] = *(const short8*)(bfA + (size_t)arow * D + ks * 32 + q * 8);
        #pragma unroll
        for (int reg = 0; reg < 4; ++reg)
            rowlab[tr][reg] = labels[rw + tr * 16 + q * 4 + reg];
    }

    float tot_a[2][4] = {{0.f,0.f,0.f,0.f},{0.f,0.f,0.f,0.f}};
    float pos_a[2][4] = {{0.f,0.f,0.f,0.f},{0.f,0.f,0.f,0.f}};

    for (int it = 0; it < 4; ++it) {
        const int cbase = blockIdx.y * 512 + it * 128;

        // ---- stage 128x128 tile via global_load_lds (16B, zero VALU data path)
        // Wave w owns LDS slots [w*512, w*512+512); slot = w*512 + j*64 + lane.
        // Slot s holds row (s>>4), chunk (s&15)^(row&15)  -> swizzle on the
        // GLOBAL address side, LDS dest is uniform base + lane*16.
        #pragma unroll
        for (int j = 0; j < 8; ++j) {
            const int brow  = wave * 32 + j * 4 + r4;
            const int chunk = c ^ ((j * 4 + r4) & 15);   // brow&15 == (j*4+r4)&15
            const unsigned short* g = bfB + (size_t)(cbase + brow) * D + chunk * 8;
            __builtin_amdgcn_global_load_lds(
                (const __attribute__((address_space(1))) void*)g,
                (__attribute__((address_space(3))) void*)&ldsB[wave * 512 + j * 64],
                16, 0, 0);
        }
        int collab[8];
        #pragma unroll
        for (int tc = 0; tc < 8; ++tc) collab[tc] = labels[cbase + tc * 16 + c];
        __syncthreads();   // barrier drains vmcnt for the LDS-DMA

        // ---- MFMA: 2 tile-rows x 8 tile-cols, K=128 in 4 steps ----
        float4v acc[2][8];
        #pragma unroll
        for (int tr = 0; tr < 2; ++tr)
            #pragma unroll
            for (int tc = 0; tc < 8; ++tc) {
                float4v z = {0.f, 0.f, 0.f, 0.f};
                acc[tr][tc] = z;
            }

        const short8* ldsS = (const short8*)ldsB;
        #pragma unroll
        for (int ks = 0; ks < 4; ++ks) {
            // byte addr = (tc*16+c)*256 + ((ks*4+q)^c)*16  -> base + tc*4096 imm
            const short8* pk = ldsS + c * 16 + ((ks * 4 + q) ^ c);
            #pragma unroll
            for (int tc = 0; tc < 8; ++tc) {
                short8 b = pk[tc * 256];
                #pragma unroll
                for (int tr = 0; tr < 2; ++tr)
                    acc[tr][tc] = __builtin_amdgcn_mfma_f32_16x16x32_bf16(
                        afrag[tr][ks], b, acc[tr][tc], 0, 0, 0);
            }
        }

        // ---- epilogue: exp2, diagonal/label masking, per-row accumulate ----
        #pragma unroll
        for (int tr = 0; tr < 2; ++tr) {
            const int rtile = rw + tr * 16;
            #pragma unroll
            for (int tc = 0; tc < 8; ++tc) {
                const bool diag_tile = (rtile == cbase + tc * 16);  // wave-uniform
                const int lc = collab[tc];
                #pragma unroll
                for (int reg = 0; reg < 4; ++reg) {
                    float v = EXP2(acc[tr][tc][reg]);
                    if (diag_tile && (q * 4 + reg) == c) v = 0.f;  // r == c
                    tot_a[tr][reg] += v;
                    if (rowlab[tr][reg] == lc) pos_a[tr][reg] += v;
                }
            }
        }
        __syncthreads();
    }

    // ---- reduce over the 16 column-lanes, one atomic per row ----
    #pragma unroll
    for (int tr = 0; tr < 2; ++tr)
        #pragma unroll
        for (int reg = 0; reg < 4; ++reg) {
            float t = tot_a[tr][reg];
            float p = pos_a[tr][reg];
            #pragma unroll
            for (int m = 1; m < 16; m <<= 1) {
                t += __shfl_xor(t, m, 64);
                p += __shfl_xor(p, m, 64);
            }
            if (c == 0) {
                const int r = rw + tr * 16 + q * 4 + reg;
                atomicAdd(&tot[r], t);
                atomicAdd(&pos[r], p);
            }
        }

    // ---- last-block finalize (ticket pattern) ----
    __threadfence();
    __syncthreads();
    if (tid == 0)
        s_ticket = __hip_atomic_fetch_add(ticket, 1, __ATOMIC_ACQ_REL,
                                          __HIP_MEMORY_SCOPE_AGENT);
    __syncthreads();
    if (s_ticket != 64 * 16 - 1) return;

    __threadfence();
    float lsum = 0.f, lcnt = 0.f;
    for (int i = tid; i < N; i += 256) {
        const float t = __hip_atomic_load(&tot[i], __ATOMIC_RELAXED,
                                          __HIP_MEMORY_SCOPE_AGENT);
        const float p = __hip_atomic_load(&pos[i], __ATOMIC_RELAXED,
                                          __HIP_MEMORY_SCOPE_AGENT);
        const float loss = -__logf(p / (t + 1e-8f) + 1e-8f);
        if (p > 0.f) { lsum += loss; lcnt += 1.f; }   // valid <=> pos>0
    }
    #pragma unroll
    for (int m = 1; m < 64; m <<= 1) {
        lsum += __shfl_xor(lsum, m, 64);
        lcnt += __shfl_xor(lcnt, m, 64);
    }
    if (lane == 0) { sred[0][wave] = lsum; sred[1][wave] = lcnt; }
    __syncthreads();
    if (tid == 0) {
        const float s = sred[0][0] + sred[0][1] + sred[0][2] + sred[0][3];
        const float n = sred[1][0] + sred[1][1] + sred[1][2] + sred[1][3];
        out[0] = (n > 0.f) ? s / fmaxf(n, 1.f) : 0.f;
    }
}

extern "C" void kernel_launch(void* const* d_in, const int* in_sizes, int n_in,
                              void* d_out, int out_size, void* d_ws, size_t ws_size,
                              hipStream_t stream) {
    const float* emb  = (const float*)d_in[0];
    const int* labels = (const int*)d_in[1];
    unsigned short* bfB = (unsigned short*)d_ws;                       // 2 MB
    unsigned short* bfA = bfB + (size_t)N * D;                         // 2 MB
    float* tot    = (float*)(bfA + (size_t)N * D);
    float* pos    = tot + N;
    int*   ticket = (int*)(pos + N);

    cl_prep<<<256, 256, 0, stream>>>(emb, bfB, bfA, tot, ticket);
    cl_main<<<dim3(64, 16), 256, 0, stream>>>(bfA, bfB, labels, tot, pos,
                                              ticket, (float*)d_out);
}

// Round 4
// 172.813 us; speedup vs baseline: 1.5906x; 1.1372x over previous
//
#include <hip/hip_runtime.h>

#define N 8192
#define D 128
// (1/0.07) * log2(e): fold temperature AND base-2 conversion into A-side scale
#define SCALE_A 20.6098592f

using short8  = __attribute__((ext_vector_type(8))) short;
using float4v = __attribute__((ext_vector_type(4))) float;

#if __has_builtin(__builtin_amdgcn_exp2f)
#define EXP2(x) __builtin_amdgcn_exp2f(x)
#else
#define EXP2(x) __expf((x) * 0.69314718f)
#endif

// float -> bf16 (RNE) as raw ushort
static __device__ inline unsigned int f2bf(float f) {
    union { float f; unsigned int u; } x;
    x.f = f;
    unsigned int u = x.u;
    return (u + 0x7FFFu + ((u >> 16) & 1u)) >> 16;
}

// Pre-pass: emb fp32 -> bf16 (unscaled, B-side) and bf16*SCALE_A (A-side).
// Also zeroes tot/pos and the ticket. 65536 threads x 16 elements.
__global__ __launch_bounds__(256) void cl_prep(
    const float* __restrict__ emb, unsigned short* __restrict__ bfB,
    unsigned short* __restrict__ bfA, float* __restrict__ tot,
    int* __restrict__ ticket)
{
    const int t = blockIdx.x * 256 + threadIdx.x;
    const float* p = emb + (size_t)t * 16;
    uint4 ob[2], oa[2];
    #pragma unroll
    for (int h = 0; h < 2; ++h) {
        float4v f0 = *(const float4v*)(p + h * 8);
        float4v f1 = *(const float4v*)(p + h * 8 + 4);
        ob[h].x = f2bf(f0[0]) | (f2bf(f0[1]) << 16);
        ob[h].y = f2bf(f0[2]) | (f2bf(f0[3]) << 16);
        ob[h].z = f2bf(f1[0]) | (f2bf(f1[1]) << 16);
        ob[h].w = f2bf(f1[2]) | (f2bf(f1[3]) << 16);
        oa[h].x = f2bf(f0[0] * SCALE_A) | (f2bf(f0[1] * SCALE_A) << 16);
        oa[h].y = f2bf(f0[2] * SCALE_A) | (f2bf(f0[3] * SCALE_A) << 16);
        oa[h].z = f2bf(f1[0] * SCALE_A) | (f2bf(f1[1] * SCALE_A) << 16);
        oa[h].w = f2bf(f1[2] * SCALE_A) | (f2bf(f1[3] * SCALE_A) << 16);
    }
    ((uint4*)bfB)[t * 2]     = ob[0];
    ((uint4*)bfB)[t * 2 + 1] = ob[1];
    ((uint4*)bfA)[t * 2]     = oa[0];
    ((uint4*)bfA)[t * 2 + 1] = oa[1];
    if (t < 2 * N) tot[t] = 0.f;    // tot and pos are contiguous
    if (t == 0) *ticket = 0;
}

// Each block: 128 rows x 512 cols. Grid (64,16) = 1024 blocks.
// exp2(dot(A_scaled, B)) == exp(sim/T). Last block (ticket) finalizes.
// NOTE: register floor of this kernel is ~190 unified VGPR+AGPR.
// (256,2) is the max occupancy bound that does NOT spill; (256,3) spilled
// ~24 regs (R3: WRITE_SIZE 24.6 MB, dur 147us), (256,4) spilled ~60 (R2).
__global__ __launch_bounds__(256, 2) void cl_main(
    const unsigned short* __restrict__ bfA, const unsigned short* __restrict__ bfB,
    const int* __restrict__ labels,
    float* __restrict__ tot, float* __restrict__ pos,
    int* __restrict__ ticket, float* __restrict__ out)
{
    __shared__ uint4 ldsB[128 * 16];  // 128x128 bf16 tile, 16B chunks, XOR-swizzled
    __shared__ float sred[2][4];
    __shared__ int s_ticket;

    const int tid  = threadIdx.x;
    const int lane = tid & 63;
    const int wave = tid >> 6;
    const int q    = lane >> 4;   // quad id 0..3
    const int c    = lane & 15;
    const int r4   = lane >> 4;   // staging row-within-group
    const int rw   = blockIdx.x * 128 + wave * 32;

    // ---- A fragments: 16B loads from prescaled bf16 array, once per block ----
    // A-operand layout (16x16x32): m = lane&15, k = q*8 + j
    short8 afrag[2][4];
    int rowlab[2][4];
    #pragma unroll
    for (int tr = 0; tr < 2; ++tr) {
        const int arow = rw + tr * 16 + c;
        #pragma unroll
        for (int ks = 0; ks < 4; ++ks)
            afrag[tr][ks] = *(const short8*)(bfA + (size_t)arow * D + ks * 32 + q * 8);
        #pragma unroll
        for (int reg = 0; reg < 4; ++reg)
            rowlab[tr][reg] = labels[rw + tr * 16 + q * 4 + reg];
    }

    float tot_a[2][4] = {{0.f,0.f,0.f,0.f},{0.f,0.f,0.f,0.f}};
    float pos_a[2][4] = {{0.f,0.f,0.f,0.f},{0.f,0.f,0.f,0.f}};

    for (int it = 0; it < 4; ++it) {
        const int cbase = blockIdx.y * 512 + it * 128;

        // ---- stage 128x128 tile via global_load_lds (16B, zero VALU data path)
        // Wave w owns LDS slots [w*512, w*512+512); slot = w*512 + j*64 + lane.
        // Swizzle applied on the GLOBAL address side; LDS dest is uniform
        // base + lane*16 (the only layout global_load_lds supports).
        #pragma unroll
        for (int j = 0; j < 8; ++j) {
            const int brow  = wave * 32 + j * 4 + r4;
            const int chunk = c ^ ((j * 4 + r4) & 15);   // brow&15 == (j*4+r4)&15
            const unsigned short* g = bfB + (size_t)(cbase + brow) * D + chunk * 8;
            __builtin_amdgcn_global_load_lds(
                (const __attribute__((address_space(1))) void*)g,
                (__attribute__((address_space(3))) void*)&ldsB[wave * 512 + j * 64],
                16, 0, 0);
        }
        int collab[8];
        #pragma unroll
        for (int tc = 0; tc < 8; ++tc) collab[tc] = labels[cbase + tc * 16 + c];
        __syncthreads();   // barrier drains vmcnt for the LDS-DMA

        // ---- MFMA: 2 tile-rows x 8 tile-cols, K=128 in 4 steps ----
        float4v acc[2][8];
        #pragma unroll
        for (int tr = 0; tr < 2; ++tr)
            #pragma unroll
            for (int tc = 0; tc < 8; ++tc) {
                float4v z = {0.f, 0.f, 0.f, 0.f};
                acc[tr][tc] = z;
            }

        const short8* ldsS = (const short8*)ldsB;
        #pragma unroll
        for (int ks = 0; ks < 4; ++ks) {
            // slot = (tc*16+c)*16 + ((ks*4+q)^c)  -> base + tc*4096B immediates
            const short8* pk = ldsS + c * 16 + ((ks * 4 + q) ^ c);
            #pragma unroll
            for (int tc = 0; tc < 8; ++tc) {
                short8 b = pk[tc * 256];
                #pragma unroll
                for (int tr = 0; tr < 2; ++tr)
                    acc[tr][tc] = __builtin_amdgcn_mfma_f32_16x16x32_bf16(
                        afrag[tr][ks], b, acc[tr][tc], 0, 0, 0);
            }
        }

        // ---- epilogue: exp2, diagonal/label masking, per-row accumulate ----
        #pragma unroll
        for (int tr = 0; tr < 2; ++tr) {
            const int rtile = rw + tr * 16;
            #pragma unroll
            for (int tc = 0; tc < 8; ++tc) {
                const bool diag_tile = (rtile == cbase + tc * 16);  // wave-uniform
                const int lc = collab[tc];
                #pragma unroll
                for (int reg = 0; reg < 4; ++reg) {
                    float v = EXP2(acc[tr][tc][reg]);
                    if (diag_tile && (q * 4 + reg) == c) v = 0.f;  // r == c
                    tot_a[tr][reg] += v;
                    if (rowlab[tr][reg] == lc) pos_a[tr][reg] += v;
                }
            }
        }
        __syncthreads();
    }

    // ---- reduce over the 16 column-lanes, one atomic per row ----
    #pragma unroll
    for (int tr = 0; tr < 2; ++tr)
        #pragma unroll
        for (int reg = 0; reg < 4; ++reg) {
            float t = tot_a[tr][reg];
            float p = pos_a[tr][reg];
            #pragma unroll
            for (int m = 1; m < 16; m <<= 1) {
                t += __shfl_xor(t, m, 64);
                p += __shfl_xor(p, m, 64);
            }
            if (c == 0) {
                const int r = rw + tr * 16 + q * 4 + reg;
                atomicAdd(&tot[r], t);
                atomicAdd(&pos[r], p);
            }
        }

    // ---- last-block finalize (ticket pattern) ----
    __threadfence();
    __syncthreads();
    if (tid == 0)
        s_ticket = __hip_atomic_fetch_add(ticket, 1, __ATOMIC_ACQ_REL,
                                          __HIP_MEMORY_SCOPE_AGENT);
    __syncthreads();
    if (s_ticket != 64 * 16 - 1) return;

    __threadfence();
    float lsum = 0.f, lcnt = 0.f;
    for (int i = tid; i < N; i += 256) {
        const float t = __hip_atomic_load(&tot[i], __ATOMIC_RELAXED,
                                          __HIP_MEMORY_SCOPE_AGENT);
        const float p = __hip_atomic_load(&pos[i], __ATOMIC_RELAXED,
                                          __HIP_MEMORY_SCOPE_AGENT);
        const float loss = -__logf(p / (t + 1e-8f) + 1e-8f);
        if (p > 0.f) { lsum += loss; lcnt += 1.f; }   // valid <=> pos>0
    }
    #pragma unroll
    for (int m = 1; m < 64; m <<= 1) {
        lsum += __shfl_xor(lsum, m, 64);
        lcnt += __shfl_xor(lcnt, m, 64);
    }
    if (lane == 0) { sred[0][wave] = lsum; sred[1][wave] = lcnt; }
    __syncthreads();
    if (tid == 0) {
        const float s = sred[0][0] + sred[0][1] + sred[0][2] + sred[0][3];
        const float n = sred[1][0] + sred[1][1] + sred[1][2] + sred[1][3];
        out[0] = (n > 0.f) ? s / fmaxf(n, 1.f) : 0.f;
    }
}

extern "C" void kernel_launch(void* const* d_in, const int* in_sizes, int n_in,
                              void* d_out, int out_size, void* d_ws, size_t ws_size,
                              hipStream_t stream) {
    const float* emb  = (const float*)d_in[0];
    const int* labels = (const int*)d_in[1];
    unsigned short* bfB = (unsigned short*)d_ws;                       // 2 MB
    unsigned short* bfA = bfB + (size_t)N * D;                         // 2 MB
    float* tot    = (float*)(bfA + (size_t)N * D);
    float* pos    = tot + N;
    int*   ticket = (int*)(pos + N);

    cl_prep<<<256, 256, 0, stream>>>(emb, bfB, bfA, tot, ticket);
    cl_main<<<dim3(64, 16), 256, 0, stream>>>(bfA, bfB, labels, tot, pos,
                                              ticket, (float*)d_out);
}

// Round 5
// 91.980 us; speedup vs baseline: 2.9884x; 1.8788x over previous
//
#include <hip/hip_runtime.h>

#define N 8192
#define D 128
// (1/0.07) * log2(e): fold temperature AND base-2 conversion into A-side scale
#define SCALE_A 20.6098592f
#define NBX 64
#define NBY 8
#define NBLK (NBX * NBY)

using short8  = __attribute__((ext_vector_type(8))) short;
using float4v = __attribute__((ext_vector_type(4))) float;

#if __has_builtin(__builtin_amdgcn_exp2f)
#define EXP2(x) __builtin_amdgcn_exp2f(x)
#else
#define EXP2(x) __expf((x) * 0.69314718f)
#endif

// float -> bf16 (RNE) as raw ushort
static __device__ inline unsigned int f2bf(float f) {
    union { float f; unsigned int u; } x;
    x.f = f;
    unsigned int u = x.u;
    return (u + 0x7FFFu + ((u >> 16) & 1u)) >> 16;
}

// Pre-pass: emb fp32 -> bf16 (unscaled, B-side) and bf16*SCALE_A (A-side).
// Also zeroes tot/pos and the ticket. 65536 threads x 16 elements.
__global__ __launch_bounds__(256) void cl_prep(
    const float* __restrict__ emb, unsigned short* __restrict__ bfB,
    unsigned short* __restrict__ bfA, float* __restrict__ tot,
    int* __restrict__ ticket)
{
    const int t = blockIdx.x * 256 + threadIdx.x;
    const float* p = emb + (size_t)t * 16;
    uint4 ob[2], oa[2];
    #pragma unroll
    for (int h = 0; h < 2; ++h) {
        float4v f0 = *(const float4v*)(p + h * 8);
        float4v f1 = *(const float4v*)(p + h * 8 + 4);
        ob[h].x = f2bf(f0[0]) | (f2bf(f0[1]) << 16);
        ob[h].y = f2bf(f0[2]) | (f2bf(f0[3]) << 16);
        ob[h].z = f2bf(f1[0]) | (f2bf(f1[1]) << 16);
        ob[h].w = f2bf(f1[2]) | (f2bf(f1[3]) << 16);
        oa[h].x = f2bf(f0[0] * SCALE_A) | (f2bf(f0[1] * SCALE_A) << 16);
        oa[h].y = f2bf(f0[2] * SCALE_A) | (f2bf(f0[3] * SCALE_A) << 16);
        oa[h].z = f2bf(f1[0] * SCALE_A) | (f2bf(f1[1] * SCALE_A) << 16);
        oa[h].w = f2bf(f1[2] * SCALE_A) | (f2bf(f1[3] * SCALE_A) << 16);
    }
    ((uint4*)bfB)[t * 2]     = ob[0];
    ((uint4*)bfB)[t * 2 + 1] = ob[1];
    ((uint4*)bfA)[t * 2]     = oa[0];
    ((uint4*)bfA)[t * 2 + 1] = oa[1];
    if (t < 2 * N) tot[t] = 0.f;    // tot and pos are contiguous
    if (t == 0) *ticket = 0;
}

// Each block: 128 rows x 1024 cols. Grid (64,8) = 512 blocks = exactly 2/CU.
// exp2(dot(A_scaled, B)) == exp(sim/T). Last block (ticket) finalizes.
// Register floor ~190 unified VGPR+AGPR -> (256,2) is max non-spilling bound
// (R2/R3 spilled at 4 and 3 waves/EU). NO agent-scope fences anywhere: they
// emit L2 writeback/invalidate per block and thrash the read-only working set
// (R4: 119us with all pipes idle). Producer ordering = s_waitcnt vmcnt(0)
// before a RELAXED ticket add; consumer uses relaxed agent atomic loads.
__global__ __launch_bounds__(256, 2) void cl_main(
    const unsigned short* __restrict__ bfA, const unsigned short* __restrict__ bfB,
    const int* __restrict__ labels,
    float* __restrict__ tot, float* __restrict__ pos,
    int* __restrict__ ticket, float* __restrict__ out)
{
    __shared__ uint4 ldsB[128 * 16];  // 128x128 bf16 tile, 16B chunks, XOR-swizzled
    __shared__ float sred[2][4];
    __shared__ int s_ticket;

    const int tid  = threadIdx.x;
    const int lane = tid & 63;
    const int wave = tid >> 6;
    const int q    = lane >> 4;   // quad id 0..3
    const int c    = lane & 15;
    const int rw   = blockIdx.x * 128 + wave * 32;

    // ---- A fragments: 16B loads from prescaled bf16 array, once per block ----
    // A-operand layout (16x16x32): m = lane&15, k = q*8 + j
    short8 afrag[2][4];
    int rowlab[2][4];
    #pragma unroll
    for (int tr = 0; tr < 2; ++tr) {
        const int arow = rw + tr * 16 + c;
        #pragma unroll
        for (int ks = 0; ks < 4; ++ks)
            afrag[tr][ks] = *(const short8*)(bfA + (size_t)arow * D + ks * 32 + q * 8);
        #pragma unroll
        for (int reg = 0; reg < 4; ++reg)
            rowlab[tr][reg] = labels[rw + tr * 16 + q * 4 + reg];
    }

    float tot_a[2][4] = {{0.f,0.f,0.f,0.f},{0.f,0.f,0.f,0.f}};
    float pos_a[2][4] = {{0.f,0.f,0.f,0.f},{0.f,0.f,0.f,0.f}};

    for (int it = 0; it < 8; ++it) {
        const int cbase = blockIdx.y * 1024 + it * 128;

        // ---- stage 128x128 tile: bf16 uint4 load -> ds_write_b128, swizzled.
        // g = tid + i*256: 16 consecutive lanes share a row, chunk=g&15 ->
        // global perfectly coalesced; LDS slot = row*16 + (chunk^(row&15)),
        // 256B contiguous (permuted) per 16 lanes -> 2-way max, free.
        const uint4* bfB4 = (const uint4*)bfB;
        #pragma unroll
        for (int i = 0; i < 8; ++i) {
            const int g     = tid + i * 256;
            const int brow  = g >> 4;
            const int chunk = g & 15;
            uint4 u = bfB4[(size_t)(cbase + brow) * 16 + chunk];
            ldsB[brow * 16 + (chunk ^ (brow & 15))] = u;
        }
        int collab[8];
        #pragma unroll
        for (int tc = 0; tc < 8; ++tc) collab[tc] = labels[cbase + tc * 16 + c];
        __syncthreads();

        // ---- MFMA: 2 tile-rows x 8 tile-cols, K=128 in 4 steps ----
        float4v acc[2][8];
        #pragma unroll
        for (int tr = 0; tr < 2; ++tr)
            #pragma unroll
            for (int tc = 0; tc < 8; ++tc) {
                float4v z = {0.f, 0.f, 0.f, 0.f};
                acc[tr][tc] = z;
            }

        const short8* ldsS = (const short8*)ldsB;
        #pragma unroll
        for (int ks = 0; ks < 4; ++ks) {
            // slot = (tc*16+c)*16 + ((ks*4+q)^c) -> base + tc*4096B immediates
            const short8* pk = ldsS + c * 16 + ((ks * 4 + q) ^ c);
            #pragma unroll
            for (int tc = 0; tc < 8; ++tc) {
                short8 b = pk[tc * 256];
                #pragma unroll
                for (int tr = 0; tr < 2; ++tr)
                    acc[tr][tc] = __builtin_amdgcn_mfma_f32_16x16x32_bf16(
                        afrag[tr][ks], b, acc[tr][tc], 0, 0, 0);
            }
        }

        // ---- epilogue: exp2, diagonal/label masking, per-row accumulate ----
        #pragma unroll
        for (int tr = 0; tr < 2; ++tr) {
            const int rtile = rw + tr * 16;
            #pragma unroll
            for (int tc = 0; tc < 8; ++tc) {
                const bool diag_tile = (rtile == cbase + tc * 16);  // wave-uniform
                const int lc = collab[tc];
                #pragma unroll
                for (int reg = 0; reg < 4; ++reg) {
                    float v = EXP2(acc[tr][tc][reg]);
                    if (diag_tile && (q * 4 + reg) == c) v = 0.f;  // r == c
                    tot_a[tr][reg] += v;
                    if (rowlab[tr][reg] == lc) pos_a[tr][reg] += v;
                }
            }
        }
        __syncthreads();
    }

    // ---- reduce over the 16 column-lanes, one atomic per row ----
    #pragma unroll
    for (int tr = 0; tr < 2; ++tr)
        #pragma unroll
        for (int reg = 0; reg < 4; ++reg) {
            float t = tot_a[tr][reg];
            float p = pos_a[tr][reg];
            #pragma unroll
            for (int m = 1; m < 16; m <<= 1) {
                t += __shfl_xor(t, m, 64);
                p += __shfl_xor(p, m, 64);
            }
            if (c == 0) {
                const int r = rw + tr * 16 + q * 4 + reg;
                atomicAdd(&tot[r], t);   // device-scope RMW at coherent point
                atomicAdd(&pos[r], p);
            }
        }

    // ---- last-block finalize: completion-wait + relaxed ticket (NO cache ops)
    asm volatile("s_waitcnt vmcnt(0)" ::: "memory");  // our atomics committed
    __syncthreads();
    if (tid == 0)
        s_ticket = __hip_atomic_fetch_add(ticket, 1, __ATOMIC_RELAXED,
                                          __HIP_MEMORY_SCOPE_AGENT);
    __syncthreads();
    if (s_ticket != NBLK - 1) return;

    float lsum = 0.f, lcnt = 0.f;
    #pragma unroll 4
    for (int i = tid; i < N; i += 256) {
        const float t = __hip_atomic_load(&tot[i], __ATOMIC_RELAXED,
                                          __HIP_MEMORY_SCOPE_AGENT);
        const float p = __hip_atomic_load(&pos[i], __ATOMIC_RELAXED,
                                          __HIP_MEMORY_SCOPE_AGENT);
        const float loss = -__logf(p / (t + 1e-8f) + 1e-8f);
        if (p > 0.f) { lsum += loss; lcnt += 1.f; }   // valid <=> pos>0
    }
    #pragma unroll
    for (int m = 1; m < 64; m <<= 1) {
        lsum += __shfl_xor(lsum, m, 64);
        lcnt += __shfl_xor(lcnt, m, 64);
    }
    if (lane == 0) { sred[0][wave] = lsum; sred[1][wave] = lcnt; }
    __syncthreads();
    if (tid == 0) {
        const float s = sred[0][0] + sred[0][1] + sred[0][2] + sred[0][3];
        const float n = sred[1][0] + sred[1][1] + sred[1][2] + sred[1][3];
        out[0] = (n > 0.f) ? s / fmaxf(n, 1.f) : 0.f;
    }
}

extern "C" void kernel_launch(void* const* d_in, const int* in_sizes, int n_in,
                              void* d_out, int out_size, void* d_ws, size_t ws_size,
                              hipStream_t stream) {
    const float* emb  = (const float*)d_in[0];
    const int* labels = (const int*)d_in[1];
    unsigned short* bfB = (unsigned short*)d_ws;                       // 2 MB
    unsigned short* bfA = bfB + (size_t)N * D;                         // 2 MB
    float* tot    = (float*)(bfA + (size_t)N * D);
    float* pos    = tot + N;
    int*   ticket = (int*)(pos + N);

    cl_prep<<<256, 256, 0, stream>>>(emb, bfB, bfA, tot, ticket);
    cl_main<<<dim3(NBX, NBY), 256, 0, stream>>>(bfA, bfB, labels, tot, pos,
                                                ticket, (float*)d_out);
}